// Round 1
// baseline (1044.579 us; speedup 1.0000x reference)
//
#include <hip/hip_runtime.h>
#include <math.h>

#define N_NODES 100000
#define N_EDGES 1600000
#define HDIM    128
#define NCLS    10
#define NGRAPH  1000

static __device__ __forceinline__ float elu1(float x) {
  return x > 0.f ? x : (__expf(x) - 1.f);
}

// ---------- CSR build ----------

// in-degree histogram over dst (edge_index row 1)
__global__ void hist_dst(const int* __restrict__ ei, int* __restrict__ cnt) {
  int e = blockIdx.x * blockDim.x + threadIdx.x;
  if (e < N_EDGES) atomicAdd(&cnt[ei[N_EDGES + e]], 1);
}

// dinv[i] = rsqrt(in_deg + 1 self-loop)
__global__ void compute_dinv(const int* __restrict__ cnt, float* __restrict__ dinv) {
  int i = blockIdx.x * blockDim.x + threadIdx.x;
  if (i < N_NODES) dinv[i] = rsqrtf((float)(cnt[i] + 1));
}

// block-local exclusive scan: 1024 elements/block (256 thr x 4)
__global__ void scan_local(const int* __restrict__ cnt, int* __restrict__ off,
                           int* __restrict__ bsum, int n) {
  __shared__ int s[256];
  int t = threadIdx.x;
  int base = blockIdx.x * 1024 + t * 4;
  int v0 = (base + 0 < n) ? cnt[base + 0] : 0;
  int v1 = (base + 1 < n) ? cnt[base + 1] : 0;
  int v2 = (base + 2 < n) ? cnt[base + 2] : 0;
  int v3 = (base + 3 < n) ? cnt[base + 3] : 0;
  int sum = v0 + v1 + v2 + v3;
  s[t] = sum;
  __syncthreads();
#pragma unroll
  for (int d = 1; d < 256; d <<= 1) {
    int val = (t >= d) ? s[t - d] : 0;
    __syncthreads();
    s[t] += val;
    __syncthreads();
  }
  int run = s[t] - sum;  // exclusive prefix for this thread's 4-group
  if (base + 0 < n) off[base + 0] = run; run += v0;
  if (base + 1 < n) off[base + 1] = run; run += v1;
  if (base + 2 < n) off[base + 2] = run; run += v2;
  if (base + 3 < n) off[base + 3] = run;
  if (t == 255) bsum[blockIdx.x] = s[255];
}

// exclusive scan of per-block totals (nb <= 128), one block of 128 threads
__global__ void scan_blocks(const int* __restrict__ bsum, int* __restrict__ boff, int nb) {
  __shared__ int s[128];
  int t = threadIdx.x;
  int v = (t < nb) ? bsum[t] : 0;
  s[t] = v;
  __syncthreads();
#pragma unroll
  for (int d = 1; d < 128; d <<= 1) {
    int val = (t >= d) ? s[t - d] : 0;
    __syncthreads();
    s[t] += val;
    __syncthreads();
  }
  if (t < nb) boff[t] = s[t] - v;
}

// add block offsets; emit final off[] and a cursor copy for the fill pass
__global__ void scan_add(int* __restrict__ off, int* __restrict__ cursor,
                         const int* __restrict__ boff, int n, int total) {
  int i = blockIdx.x * blockDim.x + threadIdx.x;
  if (i < n) {
    int o = off[i] + boff[i >> 10];
    off[i] = o;
    cursor[i] = o;
  } else if (i == n) {
    off[n] = total;
  }
}

// scatter edges into CSR slots; also precompute norm = dinv[src]*dinv[dst]
__global__ void fill_csr(const int* __restrict__ ei, const float* __restrict__ dinv,
                         int* __restrict__ cursor, int* __restrict__ csrc,
                         float* __restrict__ cw) {
  int e = blockIdx.x * blockDim.x + threadIdx.x;
  if (e >= N_EDGES) return;
  int s = ei[e];
  int d = ei[N_EDGES + e];
  int pos = atomicAdd(&cursor[d], 1);
  csrc[pos] = s;
  cw[pos] = dinv[s] * dinv[d];
}

// ---------- graph (pooling) ranges ----------

__global__ void hist_graph(const int* __restrict__ batch, int* __restrict__ gcnt) {
  int i = blockIdx.x * blockDim.x + threadIdx.x;
  if (i < N_NODES) atomicAdd(&gcnt[batch[i]], 1);
}

// single-block exclusive scan over NGRAPH (<=1024) counts
__global__ void gscan(const int* __restrict__ gcnt, int* __restrict__ goff) {
  __shared__ int s[256];
  int t = threadIdx.x;
  int base = t * 4;
  int v0 = (base + 0 < NGRAPH) ? gcnt[base + 0] : 0;
  int v1 = (base + 1 < NGRAPH) ? gcnt[base + 1] : 0;
  int v2 = (base + 2 < NGRAPH) ? gcnt[base + 2] : 0;
  int v3 = (base + 3 < NGRAPH) ? gcnt[base + 3] : 0;
  int sum = v0 + v1 + v2 + v3;
  s[t] = sum;
  __syncthreads();
#pragma unroll
  for (int d = 1; d < 256; d <<= 1) {
    int val = (t >= d) ? s[t - d] : 0;
    __syncthreads();
    s[t] += val;
    __syncthreads();
  }
  int run = s[t] - sum;
  if (base + 0 < NGRAPH) goff[base + 0] = run; run += v0;
  if (base + 1 < NGRAPH) goff[base + 1] = run; run += v1;
  if (base + 2 < NGRAPH) goff[base + 2] = run; run += v2;
  if (base + 3 < NGRAPH) goff[base + 3] = run;
  if (t == 255) goff[NGRAPH] = s[255];  // = N_NODES
}

// ---------- GEMM: C[n,128] = A[n,128] @ W[128,128] (f32 vector ALU) ----------
// 128-row x 128-col tile per block; W staged whole in LDS (64 KB);
// 8x8 register tile per thread; cols {tx*4, 64+tx*4} keep b128 LDS reads
// contiguous across the 16 tx lanes (conflict-free).
__global__ __launch_bounds__(256, 2)
void gemm_xw(const float* __restrict__ A, const float* __restrict__ W,
             float* __restrict__ C, int nrows) {
  __shared__ float Wl[128 * 128];
  int tid = threadIdx.x;
  {
    const float4* W4 = (const float4*)W;
    float4* Wl4 = (float4*)Wl;
    for (int i = tid; i < 128 * 128 / 4; i += 256) Wl4[i] = W4[i];
  }
  __syncthreads();

  int ty = tid >> 4;   // 0..15 -> row group of 8
  int tx = tid & 15;   // 0..15 -> cols {tx*4..+4} and {64+tx*4..+4}
  int row0 = blockIdx.x * 128 + ty * 8;

  const float4* arow[8];
#pragma unroll
  for (int r = 0; r < 8; ++r) {
    int rr = row0 + r;
    if (rr > nrows - 1) rr = nrows - 1;  // clamp tail (stores are guarded)
    arow[r] = (const float4*)&A[(size_t)rr * HDIM];
  }

  float4 acc0[8], acc1[8];
#pragma unroll
  for (int r = 0; r < 8; ++r) {
    acc0[r] = make_float4(0.f, 0.f, 0.f, 0.f);
    acc1[r] = make_float4(0.f, 0.f, 0.f, 0.f);
  }

  for (int k = 0; k < 128; k += 4) {
    float4 xv[8];
#pragma unroll
    for (int r = 0; r < 8; ++r) xv[r] = arow[r][k >> 2];
#pragma unroll
    for (int kk = 0; kk < 4; ++kk) {
      const float* wrow = &Wl[(k + kk) * 128];
      float4 w0 = *(const float4*)(wrow + tx * 4);
      float4 w1 = *(const float4*)(wrow + 64 + tx * 4);
#pragma unroll
      for (int r = 0; r < 8; ++r) {
        float xs = ((const float*)&xv[r])[kk];
        acc0[r].x = fmaf(xs, w0.x, acc0[r].x);
        acc0[r].y = fmaf(xs, w0.y, acc0[r].y);
        acc0[r].z = fmaf(xs, w0.z, acc0[r].z);
        acc0[r].w = fmaf(xs, w0.w, acc0[r].w);
        acc1[r].x = fmaf(xs, w1.x, acc1[r].x);
        acc1[r].y = fmaf(xs, w1.y, acc1[r].y);
        acc1[r].z = fmaf(xs, w1.z, acc1[r].z);
        acc1[r].w = fmaf(xs, w1.w, acc1[r].w);
      }
    }
  }

#pragma unroll
  for (int r = 0; r < 8; ++r) {
    int rr = row0 + r;
    if (rr < nrows) {
      *(float4*)&C[(size_t)rr * HDIM + tx * 4] = acc0[r];
      *(float4*)&C[(size_t)rr * HDIM + 64 + tx * 4] = acc1[r];
    }
  }
}

// ---------- aggregation: out[d] = elu( sum_{e in CSR[d]} w_e * h[src_e]
//                                       + dinv[d]^2 * h[d] + bias ) ----------
// one 64-lane wave per destination node; each lane owns a float2 (features
// 2*lane, 2*lane+1) so each edge is one coalesced 512 B row read.
__global__ void aggregate(const float* __restrict__ h, const int* __restrict__ off,
                          const int* __restrict__ csrc, const float* __restrict__ cw,
                          const float* __restrict__ dinv, const float* __restrict__ bias,
                          float* __restrict__ out) {
  int gid = blockIdx.x * blockDim.x + threadIdx.x;
  int node = gid >> 6;
  int lane = gid & 63;
  if (node >= N_NODES) return;
  const float2* h2 = (const float2*)h;

  float a0 = 0.f, a1 = 0.f;
  int beg = off[node], end = off[node + 1];
  for (int e = beg; e < end; ++e) {
    int s = csrc[e];       // same address across wave -> broadcast
    float w = cw[e];
    float2 v = h2[(size_t)s * 64 + lane];
    a0 = fmaf(w, v.x, a0);
    a1 = fmaf(w, v.y, a1);
  }
  float dv = dinv[node];
  float wv = dv * dv;  // self-loop norm
  float2 vs = h2[(size_t)node * 64 + lane];
  a0 = fmaf(wv, vs.x, a0);
  a1 = fmaf(wv, vs.y, a1);

  float2 bb = ((const float2*)bias)[lane];
  float2 o;
  o.x = elu1(a0 + bb.x);
  o.y = elu1(a1 + bb.y);
  ((float2*)out)[(size_t)node * 64 + lane] = o;
}

// ---------- fused max-pool + linear head + softmax ----------
// one block (128 threads) per graph; batch is sorted so graph g owns the
// contiguous node range [goff[g], goff[g+1]).
__global__ void pool_head(const float* __restrict__ feat, const int* __restrict__ goff,
                          const float* __restrict__ Wl, const float* __restrict__ bl,
                          float* __restrict__ out) {
  int g = blockIdx.x;
  int t = threadIdx.x;
  int beg = goff[g], end = goff[g + 1];

  float m = -INFINITY;
  for (int i = beg; i < end; ++i) m = fmaxf(m, feat[(size_t)i * HDIM + t]);
  if (beg == end) m = 0.f;  // empty-segment guard (isfinite -> 0 in reference)

  __shared__ float pl[HDIM];
  __shared__ float lg[NCLS];
  pl[t] = m;
  __syncthreads();

  if (t < NCLS) {
    float acc = bl[t];
#pragma unroll
    for (int f = 0; f < HDIM; ++f) acc = fmaf(pl[f], Wl[f * NCLS + t], acc);
    lg[t] = acc;
  }
  __syncthreads();

  if (t < NCLS) {
    float mx = lg[0];
#pragma unroll
    for (int c = 1; c < NCLS; ++c) mx = fmaxf(mx, lg[c]);
    float ssum = 0.f;
#pragma unroll
    for (int c = 0; c < NCLS; ++c) ssum += __expf(lg[c] - mx);
    out[g * NCLS + t] = __expf(lg[t] - mx) / ssum;
  }
}

// ---------- launch ----------

extern "C" void kernel_launch(void* const* d_in, const int* in_sizes, int n_in,
                              void* d_out, int out_size, void* d_ws, size_t ws_size,
                              hipStream_t stream) {
  const float* x    = (const float*)d_in[0];
  const int*   ei   = (const int*)d_in[1];   // [2][E] int32 (jax x64 off)
  const int*   batch= (const int*)d_in[2];
  const float* W0 = (const float*)d_in[3]; const float* b0 = (const float*)d_in[4];
  const float* W1 = (const float*)d_in[5]; const float* b1 = (const float*)d_in[6];
  const float* W2 = (const float*)d_in[7]; const float* b2 = (const float*)d_in[8];
  const float* Wl = (const float*)d_in[9]; const float* bl = (const float*)d_in[10];
  float* out = (float*)d_out;

  char* w = (char*)d_ws;
  auto alloc = [&](size_t bytes) {
    char* p = w;
    w += (bytes + 255) & ~(size_t)255;
    return p;
  };
  int*   cnt    = (int*)  alloc((size_t)N_NODES * 4);
  int*   off    = (int*)  alloc((size_t)(N_NODES + 1) * 4);
  int*   cursor = (int*)  alloc((size_t)(N_NODES + 1) * 4);
  float* dinv   = (float*)alloc((size_t)N_NODES * 4);
  int*   bsum   = (int*)  alloc(128 * 4);
  int*   boff   = (int*)  alloc(128 * 4);
  int*   gcnt   = (int*)  alloc((size_t)NGRAPH * 4);
  int*   goff   = (int*)  alloc((size_t)(NGRAPH + 1) * 4);
  int*   csrc   = (int*)  alloc((size_t)N_EDGES * 4);
  float* cw     = (float*)alloc((size_t)N_EDGES * 4);
  float* hbuf   = (float*)alloc((size_t)N_NODES * HDIM * 4);
  float* feat   = (float*)alloc((size_t)N_NODES * HDIM * 4);
  // total ~117 MB of d_ws

  hipMemsetAsync(cnt, 0, (size_t)N_NODES * 4, stream);
  hipMemsetAsync(gcnt, 0, (size_t)NGRAPH * 4, stream);

  hist_dst<<<(N_EDGES + 255) / 256, 256, 0, stream>>>(ei, cnt);
  compute_dinv<<<(N_NODES + 255) / 256, 256, 0, stream>>>(cnt, dinv);

  int nb = (N_NODES + 1023) / 1024;  // 98
  scan_local<<<nb, 256, 0, stream>>>(cnt, off, bsum, N_NODES);
  scan_blocks<<<1, 128, 0, stream>>>(bsum, boff, nb);
  scan_add<<<(N_NODES + 1 + 255) / 256, 256, 0, stream>>>(off, cursor, boff, N_NODES, N_EDGES);
  fill_csr<<<(N_EDGES + 255) / 256, 256, 0, stream>>>(ei, dinv, cursor, csrc, cw);

  hist_graph<<<(N_NODES + 255) / 256, 256, 0, stream>>>(batch, gcnt);
  gscan<<<1, 256, 0, stream>>>(gcnt, goff);

  const float* xin = x;
  const float* Ws[3] = {W0, W1, W2};
  const float* bs[3] = {b0, b1, b2};
  for (int l = 0; l < 3; ++l) {
    gemm_xw<<<(N_NODES + 127) / 128, 256, 0, stream>>>(xin, Ws[l], hbuf, N_NODES);
    aggregate<<<((size_t)N_NODES * 64 + 255) / 256, 256, 0, stream>>>(
        hbuf, off, csrc, cw, dinv, bs[l], feat);
    xin = feat;
  }

  pool_head<<<NGRAPH, 128, 0, stream>>>(feat, goff, Wl, bl, out);
}

// Round 2
// 894.087 us; speedup vs baseline: 1.1683x; 1.1683x over previous
//
#include <hip/hip_runtime.h>
#include <math.h>

#define N_NODES 100000
#define N_EDGES 1600000
#define HDIM    128
#define NCLS    10
#define NGRAPH  1000

static __device__ __forceinline__ float elu1(float x) {
  return x > 0.f ? x : (__expf(x) - 1.f);
}

// ---------- CSR build ----------

__global__ void hist_dst(const int* __restrict__ ei, int* __restrict__ cnt) {
  int e = blockIdx.x * blockDim.x + threadIdx.x;
  if (e < N_EDGES) atomicAdd(&cnt[ei[N_EDGES + e]], 1);
}

__global__ void compute_dinv(const int* __restrict__ cnt, float* __restrict__ dinv) {
  int i = blockIdx.x * blockDim.x + threadIdx.x;
  if (i < N_NODES) dinv[i] = rsqrtf((float)(cnt[i] + 1));
}

// block-local exclusive scan: 1024 elements/block (256 thr x 4)
__global__ void scan_local(const int* __restrict__ cnt, int* __restrict__ off,
                           int* __restrict__ bsum, int n) {
  __shared__ int s[256];
  int t = threadIdx.x;
  int base = blockIdx.x * 1024 + t * 4;
  int v0 = (base + 0 < n) ? cnt[base + 0] : 0;
  int v1 = (base + 1 < n) ? cnt[base + 1] : 0;
  int v2 = (base + 2 < n) ? cnt[base + 2] : 0;
  int v3 = (base + 3 < n) ? cnt[base + 3] : 0;
  int sum = v0 + v1 + v2 + v3;
  s[t] = sum;
  __syncthreads();
#pragma unroll
  for (int d = 1; d < 256; d <<= 1) {
    int val = (t >= d) ? s[t - d] : 0;
    __syncthreads();
    s[t] += val;
    __syncthreads();
  }
  int run = s[t] - sum;
  if (base + 0 < n) off[base + 0] = run; run += v0;
  if (base + 1 < n) off[base + 1] = run; run += v1;
  if (base + 2 < n) off[base + 2] = run; run += v2;
  if (base + 3 < n) off[base + 3] = run;
  if (t == 255) bsum[blockIdx.x] = s[255];
}

__global__ void scan_blocks(const int* __restrict__ bsum, int* __restrict__ boff, int nb) {
  __shared__ int s[128];
  int t = threadIdx.x;
  int v = (t < nb) ? bsum[t] : 0;
  s[t] = v;
  __syncthreads();
#pragma unroll
  for (int d = 1; d < 128; d <<= 1) {
    int val = (t >= d) ? s[t - d] : 0;
    __syncthreads();
    s[t] += val;
    __syncthreads();
  }
  if (t < nb) boff[t] = s[t] - v;
}

__global__ void scan_add(int* __restrict__ off, int* __restrict__ cursor,
                         const int* __restrict__ boff, int n, int total) {
  int i = blockIdx.x * blockDim.x + threadIdx.x;
  if (i < n) {
    int o = off[i] + boff[i >> 10];
    off[i] = o;
    cursor[i] = o;
  } else if (i == n) {
    off[n] = total;
  }
}

__global__ void fill_csr(const int* __restrict__ ei, const float* __restrict__ dinv,
                         int* __restrict__ cursor, int* __restrict__ csrc,
                         float* __restrict__ cw) {
  int e = blockIdx.x * blockDim.x + threadIdx.x;
  if (e >= N_EDGES) return;
  int s = ei[e];
  int d = ei[N_EDGES + e];
  int pos = atomicAdd(&cursor[d], 1);
  csrc[pos] = s;
  cw[pos] = dinv[s] * dinv[d];
}

// ---------- graph (pooling) ranges ----------

__global__ void hist_graph(const int* __restrict__ batch, int* __restrict__ gcnt) {
  int i = blockIdx.x * blockDim.x + threadIdx.x;
  if (i < N_NODES) atomicAdd(&gcnt[batch[i]], 1);
}

__global__ void gscan(const int* __restrict__ gcnt, int* __restrict__ goff) {
  __shared__ int s[256];
  int t = threadIdx.x;
  int base = t * 4;
  int v0 = (base + 0 < NGRAPH) ? gcnt[base + 0] : 0;
  int v1 = (base + 1 < NGRAPH) ? gcnt[base + 1] : 0;
  int v2 = (base + 2 < NGRAPH) ? gcnt[base + 2] : 0;
  int v3 = (base + 3 < NGRAPH) ? gcnt[base + 3] : 0;
  int sum = v0 + v1 + v2 + v3;
  s[t] = sum;
  __syncthreads();
#pragma unroll
  for (int d = 1; d < 256; d <<= 1) {
    int val = (t >= d) ? s[t - d] : 0;
    __syncthreads();
    s[t] += val;
    __syncthreads();
  }
  int run = s[t] - sum;
  if (base + 0 < NGRAPH) goff[base + 0] = run; run += v0;
  if (base + 1 < NGRAPH) goff[base + 1] = run; run += v1;
  if (base + 2 < NGRAPH) goff[base + 2] = run; run += v2;
  if (base + 3 < NGRAPH) goff[base + 3] = run;
  if (t == 255) goff[NGRAPH] = s[255];
}

// ---------- GEMM: C[n,128] = A[n,128] @ W[128,128] (f32 vector ALU) ----------
// 128x128 tile/block, W whole in LDS (64 KB), 8x8 reg tile/thread.
// A loads software-pipelined even/odd so one k-step's 8 global float4 loads
// are in flight while the previous k-step's 256 FMAs execute.
__global__ __launch_bounds__(256, 2)
void gemm_xw(const float* __restrict__ A, const float* __restrict__ W,
             float* __restrict__ C, int nrows) {
  __shared__ float Wl[128 * 128];
  int tid = threadIdx.x;
  {
    const float4* W4 = (const float4*)W;
    float4* Wl4 = (float4*)Wl;
    for (int i = tid; i < 128 * 128 / 4; i += 256) Wl4[i] = W4[i];
  }
  __syncthreads();

  int ty = tid >> 4;
  int tx = tid & 15;
  int row0 = blockIdx.x * 128 + ty * 8;

  const float4* arow[8];
#pragma unroll
  for (int r = 0; r < 8; ++r) {
    int rr = row0 + r;
    if (rr > nrows - 1) rr = nrows - 1;  // clamp tail (stores are guarded)
    arow[r] = (const float4*)&A[(size_t)rr * HDIM];
  }

  float4 acc0[8], acc1[8];
#pragma unroll
  for (int r = 0; r < 8; ++r) {
    acc0[r] = make_float4(0.f, 0.f, 0.f, 0.f);
    acc1[r] = make_float4(0.f, 0.f, 0.f, 0.f);
  }

  float4 xa[8], xb[8];
#pragma unroll
  for (int r = 0; r < 8; ++r) xa[r] = arow[r][0];

#define COMPUTE4(XV, KBASE)                                          \
  {                                                                  \
    _Pragma("unroll")                                                \
    for (int kk = 0; kk < 4; ++kk) {                                 \
      const float* wrow = &Wl[((KBASE) + kk) * 128];                 \
      float4 w0 = *(const float4*)(wrow + tx * 4);                   \
      float4 w1 = *(const float4*)(wrow + 64 + tx * 4);              \
      _Pragma("unroll")                                              \
      for (int r = 0; r < 8; ++r) {                                  \
        float xs = ((const float*)&XV[r])[kk];                       \
        acc0[r].x = fmaf(xs, w0.x, acc0[r].x);                       \
        acc0[r].y = fmaf(xs, w0.y, acc0[r].y);                       \
        acc0[r].z = fmaf(xs, w0.z, acc0[r].z);                       \
        acc0[r].w = fmaf(xs, w0.w, acc0[r].w);                       \
        acc1[r].x = fmaf(xs, w1.x, acc1[r].x);                       \
        acc1[r].y = fmaf(xs, w1.y, acc1[r].y);                       \
        acc1[r].z = fmaf(xs, w1.z, acc1[r].z);                       \
        acc1[r].w = fmaf(xs, w1.w, acc1[r].w);                       \
      }                                                              \
    }                                                                \
  }

  for (int k = 0; k < 128; k += 8) {
    // prefetch k+4 while computing k
#pragma unroll
    for (int r = 0; r < 8; ++r) xb[r] = arow[r][(k >> 2) + 1];
    COMPUTE4(xa, k);
    // prefetch k+8 while computing k+4
    if (k + 8 < 128) {
#pragma unroll
      for (int r = 0; r < 8; ++r) xa[r] = arow[r][(k >> 2) + 2];
    }
    COMPUTE4(xb, k + 4);
  }
#undef COMPUTE4

#pragma unroll
  for (int r = 0; r < 8; ++r) {
    int rr = row0 + r;
    if (rr < nrows) {
      *(float4*)&C[(size_t)rr * HDIM + tx * 4] = acc0[r];
      *(float4*)&C[(size_t)rr * HDIM + 64 + tx * 4] = acc1[r];
    }
  }
}

// ---------- aggregation ----------
// one 64-lane wave per destination node; lane owns float2 (features 2l,2l+1).
// 4-way edge unroll: 4 independent 512 B gathers in flight per wave
// (latency-bound fix — R1 showed VALUBusy 15%, BW 2.7 TB/s, occupancy 75%).
__global__ __launch_bounds__(256)
void aggregate(const float* __restrict__ h, const int* __restrict__ off,
               const int* __restrict__ csrc, const float* __restrict__ cw,
               const float* __restrict__ dinv, const float* __restrict__ bias,
               float* __restrict__ out) {
  int gid = blockIdx.x * blockDim.x + threadIdx.x;
  int node = gid >> 6;
  int lane = gid & 63;
  if (node >= N_NODES) return;
  const float2* h2 = (const float2*)h;

  int beg = off[node], end = off[node + 1];
  float a0 = 0.f, a1 = 0.f;  // accumulator pair A
  float c0 = 0.f, c1 = 0.f;  // accumulator pair B (split dep chain)

  int e = beg;
  for (; e + 4 <= end; e += 4) {
    int s0 = csrc[e + 0];
    int s1 = csrc[e + 1];
    int s2 = csrc[e + 2];
    int s3 = csrc[e + 3];
    float w0 = cw[e + 0];
    float w1 = cw[e + 1];
    float w2 = cw[e + 2];
    float w3 = cw[e + 3];
    float2 v0 = h2[(size_t)s0 * 64 + lane];
    float2 v1 = h2[(size_t)s1 * 64 + lane];
    float2 v2 = h2[(size_t)s2 * 64 + lane];
    float2 v3 = h2[(size_t)s3 * 64 + lane];
    a0 = fmaf(w0, v0.x, a0); a1 = fmaf(w0, v0.y, a1);
    c0 = fmaf(w1, v1.x, c0); c1 = fmaf(w1, v1.y, c1);
    a0 = fmaf(w2, v2.x, a0); a1 = fmaf(w2, v2.y, a1);
    c0 = fmaf(w3, v3.x, c0); c1 = fmaf(w3, v3.y, c1);
  }
  if (e + 2 <= end) {
    int s0 = csrc[e + 0];
    int s1 = csrc[e + 1];
    float w0 = cw[e + 0];
    float w1 = cw[e + 1];
    float2 v0 = h2[(size_t)s0 * 64 + lane];
    float2 v1 = h2[(size_t)s1 * 64 + lane];
    a0 = fmaf(w0, v0.x, a0); a1 = fmaf(w0, v0.y, a1);
    c0 = fmaf(w1, v1.x, c0); c1 = fmaf(w1, v1.y, c1);
    e += 2;
  }
  if (e < end) {
    int s0 = csrc[e];
    float w0 = cw[e];
    float2 v0 = h2[(size_t)s0 * 64 + lane];
    a0 = fmaf(w0, v0.x, a0); a1 = fmaf(w0, v0.y, a1);
  }

  float dv = dinv[node];
  float wv = dv * dv;  // self-loop norm
  float2 vs = h2[(size_t)node * 64 + lane];
  a0 = fmaf(wv, vs.x, a0);
  a1 = fmaf(wv, vs.y, a1);

  float2 bb = ((const float2*)bias)[lane];
  float2 o;
  o.x = elu1(a0 + c0 + bb.x);
  o.y = elu1(a1 + c1 + bb.y);
  ((float2*)out)[(size_t)node * 64 + lane] = o;
}

// ---------- fused max-pool + linear head + softmax ----------
__global__ void pool_head(const float* __restrict__ feat, const int* __restrict__ goff,
                          const float* __restrict__ Wl, const float* __restrict__ bl,
                          float* __restrict__ out) {
  int g = blockIdx.x;
  int t = threadIdx.x;
  int beg = goff[g], end = goff[g + 1];

  float m = -INFINITY;
  for (int i = beg; i < end; ++i) m = fmaxf(m, feat[(size_t)i * HDIM + t]);
  if (beg == end) m = 0.f;

  __shared__ float pl[HDIM];
  __shared__ float lg[NCLS];
  pl[t] = m;
  __syncthreads();

  if (t < NCLS) {
    float acc = bl[t];
#pragma unroll
    for (int f = 0; f < HDIM; ++f) acc = fmaf(pl[f], Wl[f * NCLS + t], acc);
    lg[t] = acc;
  }
  __syncthreads();

  if (t < NCLS) {
    float mx = lg[0];
#pragma unroll
    for (int c = 1; c < NCLS; ++c) mx = fmaxf(mx, lg[c]);
    float ssum = 0.f;
#pragma unroll
    for (int c = 0; c < NCLS; ++c) ssum += __expf(lg[c] - mx);
    out[g * NCLS + t] = __expf(lg[t] - mx) / ssum;
  }
}

// ---------- launch ----------

extern "C" void kernel_launch(void* const* d_in, const int* in_sizes, int n_in,
                              void* d_out, int out_size, void* d_ws, size_t ws_size,
                              hipStream_t stream) {
  const float* x    = (const float*)d_in[0];
  const int*   ei   = (const int*)d_in[1];
  const int*   batch= (const int*)d_in[2];
  const float* W0 = (const float*)d_in[3]; const float* b0 = (const float*)d_in[4];
  const float* W1 = (const float*)d_in[5]; const float* b1 = (const float*)d_in[6];
  const float* W2 = (const float*)d_in[7]; const float* b2 = (const float*)d_in[8];
  const float* Wl = (const float*)d_in[9]; const float* bl = (const float*)d_in[10];
  float* out = (float*)d_out;

  char* w = (char*)d_ws;
  auto alloc = [&](size_t bytes) {
    char* p = w;
    w += (bytes + 255) & ~(size_t)255;
    return p;
  };
  int*   cnt    = (int*)  alloc((size_t)N_NODES * 4);
  int*   off    = (int*)  alloc((size_t)(N_NODES + 1) * 4);
  int*   cursor = (int*)  alloc((size_t)(N_NODES + 1) * 4);
  float* dinv   = (float*)alloc((size_t)N_NODES * 4);
  int*   bsum   = (int*)  alloc(128 * 4);
  int*   boff   = (int*)  alloc(128 * 4);
  int*   gcnt   = (int*)  alloc((size_t)NGRAPH * 4);
  int*   goff   = (int*)  alloc((size_t)(NGRAPH + 1) * 4);
  int*   csrc   = (int*)  alloc((size_t)N_EDGES * 4);
  float* cw     = (float*)alloc((size_t)N_EDGES * 4);
  float* hbuf   = (float*)alloc((size_t)N_NODES * HDIM * 4);
  float* feat   = (float*)alloc((size_t)N_NODES * HDIM * 4);

  hipMemsetAsync(cnt, 0, (size_t)N_NODES * 4, stream);
  hipMemsetAsync(gcnt, 0, (size_t)NGRAPH * 4, stream);

  hist_dst<<<(N_EDGES + 255) / 256, 256, 0, stream>>>(ei, cnt);
  compute_dinv<<<(N_NODES + 255) / 256, 256, 0, stream>>>(cnt, dinv);

  int nb = (N_NODES + 1023) / 1024;
  scan_local<<<nb, 256, 0, stream>>>(cnt, off, bsum, N_NODES);
  scan_blocks<<<1, 128, 0, stream>>>(bsum, boff, nb);
  scan_add<<<(N_NODES + 1 + 255) / 256, 256, 0, stream>>>(off, cursor, boff, N_NODES, N_EDGES);
  fill_csr<<<(N_EDGES + 255) / 256, 256, 0, stream>>>(ei, dinv, cursor, csrc, cw);

  hist_graph<<<(N_NODES + 255) / 256, 256, 0, stream>>>(batch, gcnt);
  gscan<<<1, 256, 0, stream>>>(gcnt, goff);

  const float* xin = x;
  const float* Ws[3] = {W0, W1, W2};
  const float* bs[3] = {b0, b1, b2};
  for (int l = 0; l < 3; ++l) {
    gemm_xw<<<(N_NODES + 127) / 128, 256, 0, stream>>>(xin, Ws[l], hbuf, N_NODES);
    aggregate<<<((size_t)N_NODES * 64 + 255) / 256, 256, 0, stream>>>(
        hbuf, off, csrc, cw, dinv, bs[l], feat);
    xin = feat;
  }

  pool_head<<<NGRAPH, 128, 0, stream>>>(feat, goff, Wl, bl, out);
}

// Round 3
// 870.725 us; speedup vs baseline: 1.1997x; 1.0268x over previous
//
#include <hip/hip_runtime.h>
#include <math.h>

#define N_NODES 100000
#define N_EDGES 1600000
#define HDIM    128
#define NCLS    10
#define NGRAPH  1000

static __device__ __forceinline__ float elu1(float x) {
  return x > 0.f ? x : (__expf(x) - 1.f);
}

// ---------- CSR build ----------

// fused: in-degree histogram over dst + graph-size histogram over batch
__global__ void hist_fused(const int* __restrict__ ei, const int* __restrict__ batch,
                           int* __restrict__ cnt, int* __restrict__ gcnt) {
  int e = blockIdx.x * blockDim.x + threadIdx.x;
  if (e < N_EDGES) atomicAdd(&cnt[ei[N_EDGES + e]], 1);
  if (e < N_NODES) atomicAdd(&gcnt[batch[e]], 1);
}

// block-local exclusive scan: 1024 elements/block (256 thr x 4); also emits
// dinv[i] = rsqrt(deg_in + 1) while cnt is in registers.
__global__ void scan_local(const int* __restrict__ cnt, int* __restrict__ off,
                           int* __restrict__ bsum, float* __restrict__ dinv, int n) {
  __shared__ int s[256];
  int t = threadIdx.x;
  int base = blockIdx.x * 1024 + t * 4;
  int v0 = (base + 0 < n) ? cnt[base + 0] : 0;
  int v1 = (base + 1 < n) ? cnt[base + 1] : 0;
  int v2 = (base + 2 < n) ? cnt[base + 2] : 0;
  int v3 = (base + 3 < n) ? cnt[base + 3] : 0;
  if (base + 0 < n) dinv[base + 0] = rsqrtf((float)(v0 + 1));
  if (base + 1 < n) dinv[base + 1] = rsqrtf((float)(v1 + 1));
  if (base + 2 < n) dinv[base + 2] = rsqrtf((float)(v2 + 1));
  if (base + 3 < n) dinv[base + 3] = rsqrtf((float)(v3 + 1));
  int sum = v0 + v1 + v2 + v3;
  s[t] = sum;
  __syncthreads();
#pragma unroll
  for (int d = 1; d < 256; d <<= 1) {
    int val = (t >= d) ? s[t - d] : 0;
    __syncthreads();
    s[t] += val;
    __syncthreads();
  }
  int run = s[t] - sum;
  if (base + 0 < n) off[base + 0] = run; run += v0;
  if (base + 1 < n) off[base + 1] = run; run += v1;
  if (base + 2 < n) off[base + 2] = run; run += v2;
  if (base + 3 < n) off[base + 3] = run;
  if (t == 255) bsum[blockIdx.x] = s[255];
}

__global__ void scan_blocks(const int* __restrict__ bsum, int* __restrict__ boff, int nb) {
  __shared__ int s[128];
  int t = threadIdx.x;
  int v = (t < nb) ? bsum[t] : 0;
  s[t] = v;
  __syncthreads();
#pragma unroll
  for (int d = 1; d < 128; d <<= 1) {
    int val = (t >= d) ? s[t - d] : 0;
    __syncthreads();
    s[t] += val;
    __syncthreads();
  }
  if (t < nb) boff[t] = s[t] - v;
}

__global__ void scan_add(int* __restrict__ off, int* __restrict__ cursor,
                         const int* __restrict__ boff, int n, int total) {
  int i = blockIdx.x * blockDim.x + threadIdx.x;
  if (i < n) {
    int o = off[i] + boff[i >> 10];
    off[i] = o;
    cursor[i] = o;
  } else if (i == n) {
    off[n] = total;
  }
}

__global__ void fill_csr(const int* __restrict__ ei, const float* __restrict__ dinv,
                         int* __restrict__ cursor, int* __restrict__ csrc,
                         float* __restrict__ cw) {
  int e = blockIdx.x * blockDim.x + threadIdx.x;
  if (e >= N_EDGES) return;
  int s = ei[e];
  int d = ei[N_EDGES + e];
  int pos = atomicAdd(&cursor[d], 1);
  csrc[pos] = s;
  cw[pos] = dinv[s] * dinv[d];
}

// ---------- graph (pooling) ranges ----------

__global__ void gscan(const int* __restrict__ gcnt, int* __restrict__ goff) {
  __shared__ int s[256];
  int t = threadIdx.x;
  int base = t * 4;
  int v0 = (base + 0 < NGRAPH) ? gcnt[base + 0] : 0;
  int v1 = (base + 1 < NGRAPH) ? gcnt[base + 1] : 0;
  int v2 = (base + 2 < NGRAPH) ? gcnt[base + 2] : 0;
  int v3 = (base + 3 < NGRAPH) ? gcnt[base + 3] : 0;
  int sum = v0 + v1 + v2 + v3;
  s[t] = sum;
  __syncthreads();
#pragma unroll
  for (int d = 1; d < 256; d <<= 1) {
    int val = (t >= d) ? s[t - d] : 0;
    __syncthreads();
    s[t] += val;
    __syncthreads();
  }
  int run = s[t] - sum;
  if (base + 0 < NGRAPH) goff[base + 0] = run; run += v0;
  if (base + 1 < NGRAPH) goff[base + 1] = run; run += v1;
  if (base + 2 < NGRAPH) goff[base + 2] = run; run += v2;
  if (base + 3 < NGRAPH) goff[base + 3] = run;
  if (t == 255) goff[NGRAPH] = s[255];
}

// ---------- GEMM: C[n,128] = A[n,128] @ W[128,128] (f32 vector ALU) ----------
__global__ __launch_bounds__(256, 2)
void gemm_xw(const float* __restrict__ A, const float* __restrict__ W,
             float* __restrict__ C, int nrows) {
  __shared__ float Wl[128 * 128];
  int tid = threadIdx.x;
  {
    const float4* W4 = (const float4*)W;
    float4* Wl4 = (float4*)Wl;
    for (int i = tid; i < 128 * 128 / 4; i += 256) Wl4[i] = W4[i];
  }
  __syncthreads();

  int ty = tid >> 4;
  int tx = tid & 15;
  int row0 = blockIdx.x * 128 + ty * 8;

  const float4* arow[8];
#pragma unroll
  for (int r = 0; r < 8; ++r) {
    int rr = row0 + r;
    if (rr > nrows - 1) rr = nrows - 1;  // clamp tail (stores are guarded)
    arow[r] = (const float4*)&A[(size_t)rr * HDIM];
  }

  float4 acc0[8], acc1[8];
#pragma unroll
  for (int r = 0; r < 8; ++r) {
    acc0[r] = make_float4(0.f, 0.f, 0.f, 0.f);
    acc1[r] = make_float4(0.f, 0.f, 0.f, 0.f);
  }

  float4 xa[8], xb[8];
#pragma unroll
  for (int r = 0; r < 8; ++r) xa[r] = arow[r][0];

#define COMPUTE4(XV, KBASE)                                          \
  {                                                                  \
    _Pragma("unroll")                                                \
    for (int kk = 0; kk < 4; ++kk) {                                 \
      const float* wrow = &Wl[((KBASE) + kk) * 128];                 \
      float4 w0 = *(const float4*)(wrow + tx * 4);                   \
      float4 w1 = *(const float4*)(wrow + 64 + tx * 4);              \
      _Pragma("unroll")                                              \
      for (int r = 0; r < 8; ++r) {                                  \
        float xs = ((const float*)&XV[r])[kk];                       \
        acc0[r].x = fmaf(xs, w0.x, acc0[r].x);                       \
        acc0[r].y = fmaf(xs, w0.y, acc0[r].y);                       \
        acc0[r].z = fmaf(xs, w0.z, acc0[r].z);                       \
        acc0[r].w = fmaf(xs, w0.w, acc0[r].w);                       \
        acc1[r].x = fmaf(xs, w1.x, acc1[r].x);                       \
        acc1[r].y = fmaf(xs, w1.y, acc1[r].y);                       \
        acc1[r].z = fmaf(xs, w1.z, acc1[r].z);                       \
        acc1[r].w = fmaf(xs, w1.w, acc1[r].w);                       \
      }                                                              \
    }                                                                \
  }

  for (int k = 0; k < 128; k += 8) {
#pragma unroll
    for (int r = 0; r < 8; ++r) xb[r] = arow[r][(k >> 2) + 1];
    COMPUTE4(xa, k);
    if (k + 8 < 128) {
#pragma unroll
      for (int r = 0; r < 8; ++r) xa[r] = arow[r][(k >> 2) + 2];
    }
    COMPUTE4(xb, k + 4);
  }
#undef COMPUTE4

#pragma unroll
  for (int r = 0; r < 8; ++r) {
    int rr = row0 + r;
    if (rr < nrows) {
      *(float4*)&C[(size_t)rr * HDIM + tx * 4] = acc0[r];
      *(float4*)&C[(size_t)rr * HDIM + 64 + tx * 4] = acc1[r];
    }
  }
}

// ---------- aggregation ----------
// one 64-lane wave per destination node; lane owns float2 (features 2l,2l+1).
// 8-way edge unroll: 8 independent 512 B gathers in flight per wave.
// (R2: 4-way gave 172->120 us, VALUBusy 20%, FETCH unchanged -> MLP test.)
__global__ __launch_bounds__(256)
void aggregate(const float* __restrict__ h, const int* __restrict__ off,
               const int* __restrict__ csrc, const float* __restrict__ cw,
               const float* __restrict__ dinv, const float* __restrict__ bias,
               float* __restrict__ out) {
  int gid = blockIdx.x * blockDim.x + threadIdx.x;
  int node = gid >> 6;
  int lane = gid & 63;
  if (node >= N_NODES) return;
  const float2* h2 = (const float2*)h;

  int beg = off[node], end = off[node + 1];
  float a0 = 0.f, a1 = 0.f;
  float b0_ = 0.f, b1_ = 0.f;
  float c0 = 0.f, c1 = 0.f;
  float d0 = 0.f, d1 = 0.f;

  int e = beg;
  for (; e + 8 <= end; e += 8) {
    int s0 = csrc[e + 0], s1 = csrc[e + 1], s2 = csrc[e + 2], s3 = csrc[e + 3];
    int s4 = csrc[e + 4], s5 = csrc[e + 5], s6 = csrc[e + 6], s7 = csrc[e + 7];
    float w0 = cw[e + 0], w1 = cw[e + 1], w2 = cw[e + 2], w3 = cw[e + 3];
    float w4 = cw[e + 4], w5 = cw[e + 5], w6 = cw[e + 6], w7 = cw[e + 7];
    float2 v0 = h2[(size_t)s0 * 64 + lane];
    float2 v1 = h2[(size_t)s1 * 64 + lane];
    float2 v2 = h2[(size_t)s2 * 64 + lane];
    float2 v3 = h2[(size_t)s3 * 64 + lane];
    float2 v4 = h2[(size_t)s4 * 64 + lane];
    float2 v5 = h2[(size_t)s5 * 64 + lane];
    float2 v6 = h2[(size_t)s6 * 64 + lane];
    float2 v7 = h2[(size_t)s7 * 64 + lane];
    a0 = fmaf(w0, v0.x, a0); a1 = fmaf(w0, v0.y, a1);
    b0_ = fmaf(w1, v1.x, b0_); b1_ = fmaf(w1, v1.y, b1_);
    c0 = fmaf(w2, v2.x, c0); c1 = fmaf(w2, v2.y, c1);
    d0 = fmaf(w3, v3.x, d0); d1 = fmaf(w3, v3.y, d1);
    a0 = fmaf(w4, v4.x, a0); a1 = fmaf(w4, v4.y, a1);
    b0_ = fmaf(w5, v5.x, b0_); b1_ = fmaf(w5, v5.y, b1_);
    c0 = fmaf(w6, v6.x, c0); c1 = fmaf(w6, v6.y, c1);
    d0 = fmaf(w7, v7.x, d0); d1 = fmaf(w7, v7.y, d1);
  }
  if (e + 4 <= end) {
    int s0 = csrc[e + 0], s1 = csrc[e + 1], s2 = csrc[e + 2], s3 = csrc[e + 3];
    float w0 = cw[e + 0], w1 = cw[e + 1], w2 = cw[e + 2], w3 = cw[e + 3];
    float2 v0 = h2[(size_t)s0 * 64 + lane];
    float2 v1 = h2[(size_t)s1 * 64 + lane];
    float2 v2 = h2[(size_t)s2 * 64 + lane];
    float2 v3 = h2[(size_t)s3 * 64 + lane];
    a0 = fmaf(w0, v0.x, a0); a1 = fmaf(w0, v0.y, a1);
    b0_ = fmaf(w1, v1.x, b0_); b1_ = fmaf(w1, v1.y, b1_);
    c0 = fmaf(w2, v2.x, c0); c1 = fmaf(w2, v2.y, c1);
    d0 = fmaf(w3, v3.x, d0); d1 = fmaf(w3, v3.y, d1);
    e += 4;
  }
  if (e + 2 <= end) {
    int s0 = csrc[e + 0], s1 = csrc[e + 1];
    float w0 = cw[e + 0], w1 = cw[e + 1];
    float2 v0 = h2[(size_t)s0 * 64 + lane];
    float2 v1 = h2[(size_t)s1 * 64 + lane];
    a0 = fmaf(w0, v0.x, a0); a1 = fmaf(w0, v0.y, a1);
    b0_ = fmaf(w1, v1.x, b0_); b1_ = fmaf(w1, v1.y, b1_);
    e += 2;
  }
  if (e < end) {
    int s0 = csrc[e];
    float w0 = cw[e];
    float2 v0 = h2[(size_t)s0 * 64 + lane];
    a0 = fmaf(w0, v0.x, a0); a1 = fmaf(w0, v0.y, a1);
  }

  float dv = dinv[node];
  float wv = dv * dv;  // self-loop norm
  float2 vs = h2[(size_t)node * 64 + lane];
  a0 = fmaf(wv, vs.x, a0);
  a1 = fmaf(wv, vs.y, a1);

  float2 bb = ((const float2*)bias)[lane];
  float2 o;
  o.x = elu1((a0 + b0_) + (c0 + d0) + bb.x);
  o.y = elu1((a1 + b1_) + (c1 + d1) + bb.y);
  ((float2*)out)[(size_t)node * 64 + lane] = o;
}

// ---------- fused max-pool + linear head + softmax ----------
__global__ void pool_head(const float* __restrict__ feat, const int* __restrict__ goff,
                          const float* __restrict__ Wl, const float* __restrict__ bl,
                          float* __restrict__ out) {
  int g = blockIdx.x;
  int t = threadIdx.x;
  int beg = goff[g], end = goff[g + 1];

  float m = -INFINITY;
  for (int i = beg; i < end; ++i) m = fmaxf(m, feat[(size_t)i * HDIM + t]);
  if (beg == end) m = 0.f;

  __shared__ float pl[HDIM];
  __shared__ float lg[NCLS];
  pl[t] = m;
  __syncthreads();

  if (t < NCLS) {
    float acc = bl[t];
#pragma unroll
    for (int f = 0; f < HDIM; ++f) acc = fmaf(pl[f], Wl[f * NCLS + t], acc);
    lg[t] = acc;
  }
  __syncthreads();

  if (t < NCLS) {
    float mx = lg[0];
#pragma unroll
    for (int c = 1; c < NCLS; ++c) mx = fmaxf(mx, lg[c]);
    float ssum = 0.f;
#pragma unroll
    for (int c = 0; c < NCLS; ++c) ssum += __expf(lg[c] - mx);
    out[g * NCLS + t] = __expf(lg[t] - mx) / ssum;
  }
}

// ---------- launch ----------

extern "C" void kernel_launch(void* const* d_in, const int* in_sizes, int n_in,
                              void* d_out, int out_size, void* d_ws, size_t ws_size,
                              hipStream_t stream) {
  const float* x    = (const float*)d_in[0];
  const int*   ei   = (const int*)d_in[1];
  const int*   batch= (const int*)d_in[2];
  const float* W0 = (const float*)d_in[3]; const float* b0 = (const float*)d_in[4];
  const float* W1 = (const float*)d_in[5]; const float* b1 = (const float*)d_in[6];
  const float* W2 = (const float*)d_in[7]; const float* b2 = (const float*)d_in[8];
  const float* Wl = (const float*)d_in[9]; const float* bl = (const float*)d_in[10];
  float* out = (float*)d_out;

  char* w = (char*)d_ws;
  auto alloc = [&](size_t bytes) {
    char* p = w;
    w += (bytes + 255) & ~(size_t)255;
    return p;
  };
  int*   cnt    = (int*)  alloc((size_t)N_NODES * 4);
  int*   off    = (int*)  alloc((size_t)(N_NODES + 1) * 4);
  int*   cursor = (int*)  alloc((size_t)(N_NODES + 1) * 4);
  float* dinv   = (float*)alloc((size_t)N_NODES * 4);
  int*   bsum   = (int*)  alloc(128 * 4);
  int*   boff   = (int*)  alloc(128 * 4);
  int*   gcnt   = (int*)  alloc((size_t)NGRAPH * 4);
  int*   goff   = (int*)  alloc((size_t)(NGRAPH + 1) * 4);
  int*   csrc   = (int*)  alloc((size_t)N_EDGES * 4);
  float* cw     = (float*)alloc((size_t)N_EDGES * 4);
  float* hbuf   = (float*)alloc((size_t)N_NODES * HDIM * 4);
  float* feat   = (float*)alloc((size_t)N_NODES * HDIM * 4);

  hipMemsetAsync(cnt, 0, (size_t)N_NODES * 4, stream);
  hipMemsetAsync(gcnt, 0, (size_t)NGRAPH * 4, stream);

  hist_fused<<<(N_EDGES + 255) / 256, 256, 0, stream>>>(ei, batch, cnt, gcnt);

  int nb = (N_NODES + 1023) / 1024;
  scan_local<<<nb, 256, 0, stream>>>(cnt, off, bsum, dinv, N_NODES);
  scan_blocks<<<1, 128, 0, stream>>>(bsum, boff, nb);
  scan_add<<<(N_NODES + 1 + 255) / 256, 256, 0, stream>>>(off, cursor, boff, N_NODES, N_EDGES);
  fill_csr<<<(N_EDGES + 255) / 256, 256, 0, stream>>>(ei, dinv, cursor, csrc, cw);

  gscan<<<1, 256, 0, stream>>>(gcnt, goff);

  const float* xin = x;
  const float* Ws[3] = {W0, W1, W2};
  const float* bs[3] = {b0, b1, b2};
  for (int l = 0; l < 3; ++l) {
    gemm_xw<<<(N_NODES + 127) / 128, 256, 0, stream>>>(xin, Ws[l], hbuf, N_NODES);
    aggregate<<<((size_t)N_NODES * 64 + 255) / 256, 256, 0, stream>>>(
        hbuf, off, csrc, cw, dinv, bs[l], feat);
    xin = feat;
  }

  pool_head<<<NGRAPH, 128, 0, stream>>>(feat, goff, Wl, bl, out);
}

// Round 4
// 666.998 us; speedup vs baseline: 1.5661x; 1.3054x over previous
//
#include <hip/hip_runtime.h>
#include <hip/hip_fp16.h>
#include <math.h>

#define N_NODES 100000
#define N_EDGES 1600000
#define HDIM    128
#define NCLS    10
#define NGRAPH  1000

static __device__ __forceinline__ float elu1(float x) {
  return x > 0.f ? x : (__expf(x) - 1.f);
}

// ---------- CSR build ----------

// fused: in-degree histogram over dst + graph-size histogram over batch
__global__ void hist_fused(const int* __restrict__ ei, const int* __restrict__ batch,
                           int* __restrict__ cnt, int* __restrict__ gcnt) {
  int e = blockIdx.x * blockDim.x + threadIdx.x;
  if (e < N_EDGES) atomicAdd(&cnt[ei[N_EDGES + e]], 1);
  if (e < N_NODES) atomicAdd(&gcnt[batch[e]], 1);
}

// block-local exclusive scan: 1024 elements/block (256 thr x 4); also emits
// dinv[i] = rsqrt(deg_in + 1) while cnt is in registers.
__global__ void scan_local(const int* __restrict__ cnt, int* __restrict__ off,
                           int* __restrict__ bsum, float* __restrict__ dinv, int n) {
  __shared__ int s[256];
  int t = threadIdx.x;
  int base = blockIdx.x * 1024 + t * 4;
  int v0 = (base + 0 < n) ? cnt[base + 0] : 0;
  int v1 = (base + 1 < n) ? cnt[base + 1] : 0;
  int v2 = (base + 2 < n) ? cnt[base + 2] : 0;
  int v3 = (base + 3 < n) ? cnt[base + 3] : 0;
  if (base + 0 < n) dinv[base + 0] = rsqrtf((float)(v0 + 1));
  if (base + 1 < n) dinv[base + 1] = rsqrtf((float)(v1 + 1));
  if (base + 2 < n) dinv[base + 2] = rsqrtf((float)(v2 + 1));
  if (base + 3 < n) dinv[base + 3] = rsqrtf((float)(v3 + 1));
  int sum = v0 + v1 + v2 + v3;
  s[t] = sum;
  __syncthreads();
#pragma unroll
  for (int d = 1; d < 256; d <<= 1) {
    int val = (t >= d) ? s[t - d] : 0;
    __syncthreads();
    s[t] += val;
    __syncthreads();
  }
  int run = s[t] - sum;
  if (base + 0 < n) off[base + 0] = run; run += v0;
  if (base + 1 < n) off[base + 1] = run; run += v1;
  if (base + 2 < n) off[base + 2] = run; run += v2;
  if (base + 3 < n) off[base + 3] = run;
  if (t == 255) bsum[blockIdx.x] = s[255];
}

__global__ void scan_blocks(const int* __restrict__ bsum, int* __restrict__ boff, int nb) {
  __shared__ int s[128];
  int t = threadIdx.x;
  int v = (t < nb) ? bsum[t] : 0;
  s[t] = v;
  __syncthreads();
#pragma unroll
  for (int d = 1; d < 128; d <<= 1) {
    int val = (t >= d) ? s[t - d] : 0;
    __syncthreads();
    s[t] += val;
    __syncthreads();
  }
  if (t < nb) boff[t] = s[t] - v;
}

__global__ void scan_add(int* __restrict__ off, int* __restrict__ cursor,
                         const int* __restrict__ boff, int n, int total) {
  int i = blockIdx.x * blockDim.x + threadIdx.x;
  if (i < n) {
    int o = off[i] + boff[i >> 10];
    off[i] = o;
    cursor[i] = o;
  } else if (i == n) {
    off[n] = total;
  }
}

// scatter edges into CSR slots; packed (src, norm) int2 -> 1 cache line per
// edge scattered-write instead of 2 (csrc+cw separate arrays).
__global__ void fill_csr(const int* __restrict__ ei, const float* __restrict__ dinv,
                         int* __restrict__ cursor, int2* __restrict__ ecsr) {
  int e = blockIdx.x * blockDim.x + threadIdx.x;
  if (e >= N_EDGES) return;
  int s = ei[e];
  int d = ei[N_EDGES + e];
  int pos = atomicAdd(&cursor[d], 1);
  ecsr[pos] = make_int2(s, __float_as_int(dinv[s] * dinv[d]));
}

// ---------- graph (pooling) ranges ----------

__global__ void gscan(const int* __restrict__ gcnt, int* __restrict__ goff) {
  __shared__ int s[256];
  int t = threadIdx.x;
  int base = t * 4;
  int v0 = (base + 0 < NGRAPH) ? gcnt[base + 0] : 0;
  int v1 = (base + 1 < NGRAPH) ? gcnt[base + 1] : 0;
  int v2 = (base + 2 < NGRAPH) ? gcnt[base + 2] : 0;
  int v3 = (base + 3 < NGRAPH) ? gcnt[base + 3] : 0;
  int sum = v0 + v1 + v2 + v3;
  s[t] = sum;
  __syncthreads();
#pragma unroll
  for (int d = 1; d < 256; d <<= 1) {
    int val = (t >= d) ? s[t - d] : 0;
    __syncthreads();
    s[t] += val;
    __syncthreads();
  }
  int run = s[t] - sum;
  if (base + 0 < NGRAPH) goff[base + 0] = run; run += v0;
  if (base + 1 < NGRAPH) goff[base + 1] = run; run += v1;
  if (base + 2 < NGRAPH) goff[base + 2] = run; run += v2;
  if (base + 3 < NGRAPH) goff[base + 3] = run;
  if (t == 255) goff[NGRAPH] = s[255];
}

// ---------- GEMM: Ch[n,128](fp16) = A[n,128](f32) @ W[128,128](f32) ----------
// 128x128 tile/block, W whole in LDS (64 KB), 8x8 reg tile/thread, pipelined
// A loads. Output converted to fp16 (halves aggregate's gather bytes).
__global__ __launch_bounds__(256, 2)
void gemm_xw(const float* __restrict__ A, const float* __restrict__ W,
             __half* __restrict__ Ch, int nrows) {
  __shared__ float Wl[128 * 128];
  int tid = threadIdx.x;
  {
    const float4* W4 = (const float4*)W;
    float4* Wl4 = (float4*)Wl;
    for (int i = tid; i < 128 * 128 / 4; i += 256) Wl4[i] = W4[i];
  }
  __syncthreads();

  int ty = tid >> 4;
  int tx = tid & 15;
  int row0 = blockIdx.x * 128 + ty * 8;

  const float4* arow[8];
#pragma unroll
  for (int r = 0; r < 8; ++r) {
    int rr = row0 + r;
    if (rr > nrows - 1) rr = nrows - 1;  // clamp tail (stores are guarded)
    arow[r] = (const float4*)&A[(size_t)rr * HDIM];
  }

  float4 acc0[8], acc1[8];
#pragma unroll
  for (int r = 0; r < 8; ++r) {
    acc0[r] = make_float4(0.f, 0.f, 0.f, 0.f);
    acc1[r] = make_float4(0.f, 0.f, 0.f, 0.f);
  }

  float4 xa[8], xb[8];
#pragma unroll
  for (int r = 0; r < 8; ++r) xa[r] = arow[r][0];

#define COMPUTE4(XV, KBASE)                                          \
  {                                                                  \
    _Pragma("unroll")                                                \
    for (int kk = 0; kk < 4; ++kk) {                                 \
      const float* wrow = &Wl[((KBASE) + kk) * 128];                 \
      float4 w0 = *(const float4*)(wrow + tx * 4);                   \
      float4 w1 = *(const float4*)(wrow + 64 + tx * 4);              \
      _Pragma("unroll")                                              \
      for (int r = 0; r < 8; ++r) {                                  \
        float xs = ((const float*)&XV[r])[kk];                       \
        acc0[r].x = fmaf(xs, w0.x, acc0[r].x);                       \
        acc0[r].y = fmaf(xs, w0.y, acc0[r].y);                       \
        acc0[r].z = fmaf(xs, w0.z, acc0[r].z);                       \
        acc0[r].w = fmaf(xs, w0.w, acc0[r].w);                       \
        acc1[r].x = fmaf(xs, w1.x, acc1[r].x);                       \
        acc1[r].y = fmaf(xs, w1.y, acc1[r].y);                       \
        acc1[r].z = fmaf(xs, w1.z, acc1[r].z);                       \
        acc1[r].w = fmaf(xs, w1.w, acc1[r].w);                       \
      }                                                              \
    }                                                                \
  }

  for (int k = 0; k < 128; k += 8) {
#pragma unroll
    for (int r = 0; r < 8; ++r) xb[r] = arow[r][(k >> 2) + 1];
    COMPUTE4(xa, k);
    if (k + 8 < 128) {
#pragma unroll
      for (int r = 0; r < 8; ++r) xa[r] = arow[r][(k >> 2) + 2];
    }
    COMPUTE4(xb, k + 4);
  }
#undef COMPUTE4

#pragma unroll
  for (int r = 0; r < 8; ++r) {
    int rr = row0 + r;
    if (rr < nrows) {
      __half2 l0 = __floats2half2_rn(acc0[r].x, acc0[r].y);
      __half2 l1 = __floats2half2_rn(acc0[r].z, acc0[r].w);
      __half2 h0 = __floats2half2_rn(acc1[r].x, acc1[r].y);
      __half2 h1 = __floats2half2_rn(acc1[r].z, acc1[r].w);
      uint2 p0, p1;
      p0.x = *(unsigned*)&l0; p0.y = *(unsigned*)&l1;
      p1.x = *(unsigned*)&h0; p1.y = *(unsigned*)&h1;
      *(uint2*)&Ch[(size_t)rr * HDIM + tx * 4] = p0;
      *(uint2*)&Ch[(size_t)rr * HDIM + 64 + tx * 4] = p1;
    }
  }
}

// ---------- aggregation ----------
// one 64-lane wave per dst node; lane owns half2 (features 2l,2l+1) = 256 B
// coalesced row per edge. 8 independent gathers in flight. fp16 gather table
// (R3: fabric-bound at 512 B/row, FETCH 407 MB -> halve bytes).
__global__ __launch_bounds__(256)
void aggregate(const __half* __restrict__ h, const int* __restrict__ off,
               const int2* __restrict__ ecsr, const float* __restrict__ dinv,
               const float* __restrict__ bias, float* __restrict__ out) {
  int gid = blockIdx.x * blockDim.x + threadIdx.x;
  int node = gid >> 6;
  int lane = gid & 63;
  if (node >= N_NODES) return;
  const __half2* h2 = (const __half2*)h;

  int beg = off[node], end = off[node + 1];
  float a0 = 0.f, a1 = 0.f;
  float b0_ = 0.f, b1_ = 0.f;
  float c0 = 0.f, c1 = 0.f;
  float d0 = 0.f, d1 = 0.f;

  int e = beg;
  for (; e + 8 <= end; e += 8) {
    int2 e0 = ecsr[e + 0], e1 = ecsr[e + 1], e2 = ecsr[e + 2], e3 = ecsr[e + 3];
    int2 e4 = ecsr[e + 4], e5 = ecsr[e + 5], e6 = ecsr[e + 6], e7 = ecsr[e + 7];
    __half2 v0 = h2[(size_t)e0.x * 64 + lane];
    __half2 v1 = h2[(size_t)e1.x * 64 + lane];
    __half2 v2 = h2[(size_t)e2.x * 64 + lane];
    __half2 v3 = h2[(size_t)e3.x * 64 + lane];
    __half2 v4 = h2[(size_t)e4.x * 64 + lane];
    __half2 v5 = h2[(size_t)e5.x * 64 + lane];
    __half2 v6 = h2[(size_t)e6.x * 64 + lane];
    __half2 v7 = h2[(size_t)e7.x * 64 + lane];
    float2 f0 = __half22float2(v0), f1 = __half22float2(v1);
    float2 f2 = __half22float2(v2), f3 = __half22float2(v3);
    float2 f4 = __half22float2(v4), f5 = __half22float2(v5);
    float2 f6 = __half22float2(v6), f7 = __half22float2(v7);
    float w0 = __int_as_float(e0.y), w1 = __int_as_float(e1.y);
    float w2 = __int_as_float(e2.y), w3 = __int_as_float(e3.y);
    float w4 = __int_as_float(e4.y), w5 = __int_as_float(e5.y);
    float w6 = __int_as_float(e6.y), w7 = __int_as_float(e7.y);
    a0 = fmaf(w0, f0.x, a0); a1 = fmaf(w0, f0.y, a1);
    b0_ = fmaf(w1, f1.x, b0_); b1_ = fmaf(w1, f1.y, b1_);
    c0 = fmaf(w2, f2.x, c0); c1 = fmaf(w2, f2.y, c1);
    d0 = fmaf(w3, f3.x, d0); d1 = fmaf(w3, f3.y, d1);
    a0 = fmaf(w4, f4.x, a0); a1 = fmaf(w4, f4.y, a1);
    b0_ = fmaf(w5, f5.x, b0_); b1_ = fmaf(w5, f5.y, b1_);
    c0 = fmaf(w6, f6.x, c0); c1 = fmaf(w6, f6.y, c1);
    d0 = fmaf(w7, f7.x, d0); d1 = fmaf(w7, f7.y, d1);
  }
  if (e + 4 <= end) {
    int2 e0 = ecsr[e + 0], e1 = ecsr[e + 1], e2 = ecsr[e + 2], e3 = ecsr[e + 3];
    __half2 v0 = h2[(size_t)e0.x * 64 + lane];
    __half2 v1 = h2[(size_t)e1.x * 64 + lane];
    __half2 v2 = h2[(size_t)e2.x * 64 + lane];
    __half2 v3 = h2[(size_t)e3.x * 64 + lane];
    float2 f0 = __half22float2(v0), f1 = __half22float2(v1);
    float2 f2 = __half22float2(v2), f3 = __half22float2(v3);
    float w0 = __int_as_float(e0.y), w1 = __int_as_float(e1.y);
    float w2 = __int_as_float(e2.y), w3 = __int_as_float(e3.y);
    a0 = fmaf(w0, f0.x, a0); a1 = fmaf(w0, f0.y, a1);
    b0_ = fmaf(w1, f1.x, b0_); b1_ = fmaf(w1, f1.y, b1_);
    c0 = fmaf(w2, f2.x, c0); c1 = fmaf(w2, f2.y, c1);
    d0 = fmaf(w3, f3.x, d0); d1 = fmaf(w3, f3.y, d1);
    e += 4;
  }
  if (e + 2 <= end) {
    int2 e0 = ecsr[e + 0], e1 = ecsr[e + 1];
    __half2 v0 = h2[(size_t)e0.x * 64 + lane];
    __half2 v1 = h2[(size_t)e1.x * 64 + lane];
    float2 f0 = __half22float2(v0), f1 = __half22float2(v1);
    float w0 = __int_as_float(e0.y), w1 = __int_as_float(e1.y);
    a0 = fmaf(w0, f0.x, a0); a1 = fmaf(w0, f0.y, a1);
    b0_ = fmaf(w1, f1.x, b0_); b1_ = fmaf(w1, f1.y, b1_);
    e += 2;
  }
  if (e < end) {
    int2 e0 = ecsr[e];
    __half2 v0 = h2[(size_t)e0.x * 64 + lane];
    float2 f0 = __half22float2(v0);
    float w0 = __int_as_float(e0.y);
    a0 = fmaf(w0, f0.x, a0); a1 = fmaf(w0, f0.y, a1);
  }

  float dv = dinv[node];
  float wv = dv * dv;  // self-loop norm
  float2 vs = __half22float2(h2[(size_t)node * 64 + lane]);
  a0 = fmaf(wv, vs.x, a0);
  a1 = fmaf(wv, vs.y, a1);

  float2 bb = ((const float2*)bias)[lane];
  float2 o;
  o.x = elu1((a0 + b0_) + (c0 + d0) + bb.x);
  o.y = elu1((a1 + b1_) + (c1 + d1) + bb.y);
  ((float2*)out)[(size_t)node * 64 + lane] = o;
}

// ---------- fused max-pool + linear head + softmax ----------
__global__ void pool_head(const float* __restrict__ feat, const int* __restrict__ goff,
                          const float* __restrict__ Wl, const float* __restrict__ bl,
                          float* __restrict__ out) {
  int g = blockIdx.x;
  int t = threadIdx.x;
  int beg = goff[g], end = goff[g + 1];

  float m0 = -INFINITY, m1 = -INFINITY, m2 = -INFINITY, m3 = -INFINITY;
  int i = beg;
  for (; i + 4 <= end; i += 4) {
    m0 = fmaxf(m0, feat[(size_t)(i + 0) * HDIM + t]);
    m1 = fmaxf(m1, feat[(size_t)(i + 1) * HDIM + t]);
    m2 = fmaxf(m2, feat[(size_t)(i + 2) * HDIM + t]);
    m3 = fmaxf(m3, feat[(size_t)(i + 3) * HDIM + t]);
  }
  for (; i < end; ++i) m0 = fmaxf(m0, feat[(size_t)i * HDIM + t]);
  float m = fmaxf(fmaxf(m0, m1), fmaxf(m2, m3));
  if (beg == end) m = 0.f;

  __shared__ float pl[HDIM];
  __shared__ float lg[NCLS];
  pl[t] = m;
  __syncthreads();

  if (t < NCLS) {
    float acc = bl[t];
#pragma unroll
    for (int f = 0; f < HDIM; ++f) acc = fmaf(pl[f], Wl[f * NCLS + t], acc);
    lg[t] = acc;
  }
  __syncthreads();

  if (t < NCLS) {
    float mx = lg[0];
#pragma unroll
    for (int c = 1; c < NCLS; ++c) mx = fmaxf(mx, lg[c]);
    float ssum = 0.f;
#pragma unroll
    for (int c = 0; c < NCLS; ++c) ssum += __expf(lg[c] - mx);
    out[g * NCLS + t] = __expf(lg[t] - mx) / ssum;
  }
}

// ---------- launch ----------

extern "C" void kernel_launch(void* const* d_in, const int* in_sizes, int n_in,
                              void* d_out, int out_size, void* d_ws, size_t ws_size,
                              hipStream_t stream) {
  const float* x    = (const float*)d_in[0];
  const int*   ei   = (const int*)d_in[1];
  const int*   batch= (const int*)d_in[2];
  const float* W0 = (const float*)d_in[3]; const float* b0 = (const float*)d_in[4];
  const float* W1 = (const float*)d_in[5]; const float* b1 = (const float*)d_in[6];
  const float* W2 = (const float*)d_in[7]; const float* b2 = (const float*)d_in[8];
  const float* Wl = (const float*)d_in[9]; const float* bl = (const float*)d_in[10];
  float* out = (float*)d_out;

  char* w = (char*)d_ws;
  auto alloc = [&](size_t bytes) {
    char* p = w;
    w += (bytes + 255) & ~(size_t)255;
    return p;
  };
  int*    cnt    = (int*)   alloc((size_t)N_NODES * 4);
  int*    off    = (int*)   alloc((size_t)(N_NODES + 1) * 4);
  int*    cursor = (int*)   alloc((size_t)(N_NODES + 1) * 4);
  float*  dinv   = (float*) alloc((size_t)N_NODES * 4);
  int*    bsum   = (int*)   alloc(128 * 4);
  int*    boff   = (int*)   alloc(128 * 4);
  int*    gcnt   = (int*)   alloc((size_t)NGRAPH * 4);
  int*    goff   = (int*)   alloc((size_t)(NGRAPH + 1) * 4);
  int2*   ecsr   = (int2*)  alloc((size_t)N_EDGES * 8);
  __half* hbuf   = (__half*)alloc((size_t)N_NODES * HDIM * 2);
  float*  feat   = (float*) alloc((size_t)N_NODES * HDIM * 4);

  hipMemsetAsync(cnt, 0, (size_t)N_NODES * 4, stream);
  hipMemsetAsync(gcnt, 0, (size_t)NGRAPH * 4, stream);

  hist_fused<<<(N_EDGES + 255) / 256, 256, 0, stream>>>(ei, batch, cnt, gcnt);

  int nb = (N_NODES + 1023) / 1024;
  scan_local<<<nb, 256, 0, stream>>>(cnt, off, bsum, dinv, N_NODES);
  scan_blocks<<<1, 128, 0, stream>>>(bsum, boff, nb);
  scan_add<<<(N_NODES + 1 + 255) / 256, 256, 0, stream>>>(off, cursor, boff, N_NODES, N_EDGES);
  fill_csr<<<(N_EDGES + 255) / 256, 256, 0, stream>>>(ei, dinv, cursor, ecsr);

  gscan<<<1, 256, 0, stream>>>(gcnt, goff);

  const float* xin = x;
  const float* Ws[3] = {W0, W1, W2};
  const float* bs[3] = {b0, b1, b2};
  for (int l = 0; l < 3; ++l) {
    gemm_xw<<<(N_NODES + 127) / 128, 256, 0, stream>>>(xin, Ws[l], hbuf, N_NODES);
    aggregate<<<((size_t)N_NODES * 64 + 255) / 256, 256, 0, stream>>>(
        hbuf, off, ecsr, dinv, bs[l], feat);
    xin = feat;
  }

  pool_head<<<NGRAPH, 128, 0, stream>>>(feat, goff, Wl, bl, out);
}